// Round 3
// baseline (18692.116 us; speedup 1.0000x reference)
//
#include <hip/hip_runtime.h>
#include <hip/hip_bf16.h>

// Problem constants
#define NB 32      // batch
#define TO 64      // output tokens
#define TT 65      // decode steps (To+1)
#define TI 512     // encoder time
#define VV 10000   // vocab
#define EE 512     // embed
#define HH 512     // hidden
#define G4 2048    // 4*H
#define SOS_ID 1
#define EOS_ID 2
#define NBLK 256   // persistent-kernel grid (co-resident: 4 waves/CU on 256 CUs)

// ---------------------------------------------------------------------------
// Weight transpose: Wt[k][j] = concat(A,B)[j][k], zero-padded to Jp columns
// ---------------------------------------------------------------------------
__global__ void transpose_cat(const float* __restrict__ A, int KA,
                              const float* __restrict__ B, int KB,
                              int J, int Jp, float* __restrict__ Wt) {
    int K = KA + KB;
    long total = (long)K * Jp;
    for (long idx = (long)blockIdx.x * 256 + threadIdx.x; idx < total;
         idx += (long)gridDim.x * 256) {
        int j = (int)(idx % Jp);
        int k = (int)(idx / Jp);
        float v = 0.f;
        if (j < J) v = (k < KA) ? A[(long)j * KA + k] : B[(long)j * KB + (k - KA)];
        Wt[idx] = v;
    }
}

// ---------------------------------------------------------------------------
// Device-scope grid barrier (monotonic counter; reset by memset each call).
// Writer: __threadfence (wb L2) + release add. Reader: spin relaxed, then
// __threadfence (inv L1/L2) so normal loads see fresh data cross-XCD.
// ---------------------------------------------------------------------------
__device__ __forceinline__ void gbar(int* cnt, int& bt) {
    __syncthreads();
    bt += NBLK;
    if (threadIdx.x == 0) {
        __threadfence();
        __hip_atomic_fetch_add(cnt, 1, __ATOMIC_RELEASE, __HIP_MEMORY_SCOPE_AGENT);
        while (__hip_atomic_load(cnt, __ATOMIC_RELAXED, __HIP_MEMORY_SCOPE_AGENT) < bt)
            __builtin_amdgcn_s_sleep(2);
        __threadfence();
    }
    __syncthreads();
}

// ---------------------------------------------------------------------------
// Gates phase (device): 256 blocks x 256 thr; block owns 64 (n,m) pairs,
// thread owns one (gate, pair): sums 32 k-split partials + bias. LDS combine.
// ---------------------------------------------------------------------------
__device__ __forceinline__ void gates_phase(const float* __restrict__ part,
                                            const float* __restrict__ bi,
                                            const float* __restrict__ bh,
                                            float* __restrict__ h,
                                            float* __restrict__ c,
                                            float* __restrict__ hextra, long hoff,
                                            float* sg) {
    int tid = threadIdx.x, b = blockIdx.x;
    int e = tid & 63, g = tid >> 6;
    int idx = b * 64 + e;
    int n = idx >> 9, m = idx & 511;
    int col = g * 512 + m;
    float s = bi[col] + bh[col];
    const float* p = part + (long)n * G4 + col;
#pragma unroll 8
    for (int ks = 0; ks < 32; ks++) s += p[(long)ks * 32 * G4];
    sg[g * 64 + e] = s;
    __syncthreads();
    if (tid < 64) {
        float gi = sg[tid], gf = sg[64 + tid], gg = sg[128 + tid], go = sg[192 + tid];
        int idx2 = b * 64 + tid;
        int n2 = idx2 >> 9, m2 = idx2 & 511;
        float cv = c[idx2];
        float si = 1.f / (1.f + expf(-gi));
        float sf = 1.f / (1.f + expf(-gf));
        float so = 1.f / (1.f + expf(-go));
        float c2 = sf * cv + si * tanhf(gg);
        c[idx2] = c2;
        float hv = so * tanhf(c2);
        h[idx2] = hv;
        if (hextra) hextra[hoff + (long)n2 * 1024 + m2] = hv;
    }
    __syncthreads();
}

// ---------------------------------------------------------------------------
// Persistent decode loop: 65 steps x 8 phases, grid barrier between phases.
// ---------------------------------------------------------------------------
__global__ __launch_bounds__(256, 1) void decode_loop(
    const float* __restrict__ Wt0, const float* __restrict__ Wt1,
    const float* __restrict__ Wt2, const float* __restrict__ emb,
    const int* __restrict__ tokens, const float* __restrict__ enc,
    const float* __restrict__ b_ih0, const float* __restrict__ b_hh0,
    const float* __restrict__ b_ih_r, const float* __restrict__ b_hh_r,
    float* __restrict__ hbuf, float* __restrict__ cbuf,
    float* __restrict__ attc, float* __restrict__ scor,
    float* __restrict__ mlpin, float* __restrict__ part, int* cnt) {
    __shared__ float smem[1792];
    int tid = threadIdx.x, b = blockIdx.x;
    int bt = 0;
    float* h0 = hbuf;
    float* h1 = hbuf + NB * HH;
    float* h2 = hbuf + 2 * NB * HH;
    float* c0 = cbuf;
    float* c1 = cbuf + NB * HH;
    float* c2 = cbuf + 2 * NB * HH;
    int lane = tid & 63, wv = tid >> 6;
    int jc = b & 7, kc = b >> 3;

    for (int t = 0; t < TT; t++) {
        // ---- phase 1: gemm0 partials: K=1536, chunk 48, x=[emb|attc|h0]
        {
            int k0 = kc * 48;
            for (int idx = tid; idx < 48 * 32; idx += 256) {
                int n = idx & 31, k = idx >> 5;
                int kk = k0 + k;
                float v;
                if (kk < 512) {
                    int row = (t == 0) ? SOS_ID : tokens[n * TO + (t - 1)];
                    v = emb[(long)row * 512 + kk];
                } else if (kk < 1024) {
                    v = attc[n * 512 + (kk - 512)];
                } else {
                    v = h0[n * 512 + (kk - 1024)];
                }
                smem[k * 36 + n] = v;
            }
            __syncthreads();
            int j = jc * 256 + wv * 64 + lane;
            float acc[32];
#pragma unroll
            for (int q = 0; q < 32; q++) acc[q] = 0.f;
            const float* wp = Wt0 + (long)k0 * G4 + j;
#pragma unroll 4
            for (int k = 0; k < 48; k++) {
                float w = wp[(long)k * G4];
                const float4* xv = (const float4*)(smem + k * 36);
#pragma unroll
                for (int q = 0; q < 8; q++) {
                    float4 x4 = xv[q];
                    acc[4 * q + 0] += w * x4.x;
                    acc[4 * q + 1] += w * x4.y;
                    acc[4 * q + 2] += w * x4.z;
                    acc[4 * q + 3] += w * x4.w;
                }
            }
            float* po = part + (long)kc * 32 * G4 + j;
#pragma unroll
            for (int nn = 0; nn < 32; nn++) po[(long)nn * G4] = acc[nn];
        }
        gbar(cnt, bt);
        // ---- phase 2: gates0
        gates_phase(part, b_ih0, b_hh0, h0, c0, nullptr, 0, smem);
        gbar(cnt, bt);
        // ---- phase 3: gemm1 partials: K=1024, chunk 32, x=[h0'|h1]
        {
            int k0 = kc * 32;
            for (int idx = tid; idx < 32 * 32; idx += 256) {
                int n = idx & 31, k = idx >> 5;
                int kk = k0 + k;
                float v = (kk < 512) ? h0[n * 512 + kk] : h1[n * 512 + (kk - 512)];
                smem[k * 36 + n] = v;
            }
            __syncthreads();
            int j = jc * 256 + wv * 64 + lane;
            float acc[32];
#pragma unroll
            for (int q = 0; q < 32; q++) acc[q] = 0.f;
            const float* wp = Wt1 + (long)k0 * G4 + j;
#pragma unroll 4
            for (int k = 0; k < 32; k++) {
                float w = wp[(long)k * G4];
                const float4* xv = (const float4*)(smem + k * 36);
#pragma unroll
                for (int q = 0; q < 8; q++) {
                    float4 x4 = xv[q];
                    acc[4 * q + 0] += w * x4.x;
                    acc[4 * q + 1] += w * x4.y;
                    acc[4 * q + 2] += w * x4.z;
                    acc[4 * q + 3] += w * x4.w;
                }
            }
            float* po = part + (long)kc * 32 * G4 + j;
#pragma unroll
            for (int nn = 0; nn < 32; nn++) po[(long)nn * G4] = acc[nn];
        }
        gbar(cnt, bt);
        // ---- phase 4: gates1
        gates_phase(part, b_ih_r, b_hh_r, h1, c1, nullptr, 0, smem);
        gbar(cnt, bt);
        // ---- phase 5: gemm2 partials: K=1024, chunk 32, x=[h1'|h2]
        {
            int k0 = kc * 32;
            for (int idx = tid; idx < 32 * 32; idx += 256) {
                int n = idx & 31, k = idx >> 5;
                int kk = k0 + k;
                float v = (kk < 512) ? h1[n * 512 + kk] : h2[n * 512 + (kk - 512)];
                smem[k * 36 + n] = v;
            }
            __syncthreads();
            int j = jc * 256 + wv * 64 + lane;
            float acc[32];
#pragma unroll
            for (int q = 0; q < 32; q++) acc[q] = 0.f;
            const float* wp = Wt2 + (long)k0 * G4 + j;
#pragma unroll 4
            for (int k = 0; k < 32; k++) {
                float w = wp[(long)k * G4];
                const float4* xv = (const float4*)(smem + k * 36);
#pragma unroll
                for (int q = 0; q < 8; q++) {
                    float4 x4 = xv[q];
                    acc[4 * q + 0] += w * x4.x;
                    acc[4 * q + 1] += w * x4.y;
                    acc[4 * q + 2] += w * x4.z;
                    acc[4 * q + 3] += w * x4.w;
                }
            }
            float* po = part + (long)kc * 32 * G4 + j;
#pragma unroll
            for (int nn = 0; nn < 32; nn++) po[(long)nn * G4] = acc[nn];
        }
        gbar(cnt, bt);
        // ---- phase 6: gates2 (h2' also -> mlpin[t][:][0:512])
        gates_phase(part, b_ih_r + G4, b_hh_r + G4, h2, c2, mlpin,
                    (long)t * NB * 1024, smem);
        gbar(cnt, bt);
        // ---- phase 7: scores[n][ti] = dot(h2'[n], enc[n][ti])
        {
            int n = b >> 3;
            const float* r = h2 + n * 512;
            float4 r0 = *(const float4*)(r + lane * 8);
            float4 r1 = *(const float4*)(r + lane * 8 + 4);
            int tibase = (b & 7) * 64 + wv * 16;
#pragma unroll 2
            for (int i = 0; i < 16; i++) {
                int ti = tibase + i;
                const float* e = enc + ((long)n * TI + ti) * HH + lane * 8;
                float4 e0 = *(const float4*)e;
                float4 e1 = *(const float4*)(e + 4);
                float s = r0.x * e0.x + r0.y * e0.y + r0.z * e0.z + r0.w * e0.w +
                          r1.x * e1.x + r1.y * e1.y + r1.z * e1.z + r1.w * e1.w;
                s += __shfl_xor(s, 32);
                s += __shfl_xor(s, 16);
                s += __shfl_xor(s, 8);
                s += __shfl_xor(s, 4);
                s += __shfl_xor(s, 2);
                s += __shfl_xor(s, 1);
                if (lane == 0) scor[n * 512 + ti] = s;
            }
        }
        gbar(cnt, bt);
        // ---- phase 8: softmax + apply -> attc, mlpin[t][:][512:1024]
        {
            int n = b >> 3, hc = b & 7;
            float* sc = smem;
            float* red = smem + 512;
            float* prt = smem + 1024;
            float s0 = scor[n * 512 + tid], s1 = scor[n * 512 + 256 + tid];
            red[tid] = fmaxf(s0, s1);
            __syncthreads();
            for (int s = 128; s > 0; s >>= 1) {
                if (tid < s) red[tid] = fmaxf(red[tid], red[tid + s]);
                __syncthreads();
            }
            float m = red[0];
            __syncthreads();
            float e0 = expf(s0 - m), e1 = expf(s1 - m);
            red[tid] = e0 + e1;
            __syncthreads();
            for (int s = 128; s > 0; s >>= 1) {
                if (tid < s) red[tid] += red[tid + s];
                __syncthreads();
            }
            float inv = 1.f / red[0];
            sc[tid] = e0 * inv;
            sc[256 + tid] = e1 * inv;
            __syncthreads();
            int h = hc * 64 + lane;
            int tg = wv;
            const float* eb = enc + ((long)n * TI + tg * 128) * HH + h;
            float a = 0.f;
#pragma unroll 4
            for (int ti = 0; ti < 128; ti++) a += sc[tg * 128 + ti] * eb[(long)ti * HH];
            prt[tid] = a;
            __syncthreads();
            if (tg == 0) {
                float v = prt[tid] + prt[tid + 64] + prt[tid + 128] + prt[tid + 192];
                attc[n * 512 + h] = v;
                mlpin[((long)t * NB + n) * 1024 + 512 + h] = v;
            }
        }
        gbar(cnt, bt);
    }
}

// ---------------------------------------------------------------------------
// Full-K batched GEMM with fused bias(+tanh). Thread owns 2 j's (j0, j0+64).
// remap=0: out[row][J]; remap=1: out[(nn*TT+t)*VV + j]
// ---------------------------------------------------------------------------
__global__ void gemm_full(const float* __restrict__ Wt, int Jp, int J, int K,
                          const float* __restrict__ X,
                          const float* __restrict__ bias,
                          float* __restrict__ out, int act, int remap) {
    __shared__ float xs[64 * 36];
    int t = blockIdx.y;
    int m0 = t * 32;
    int lane = threadIdx.x & 63;
    int wv = threadIdx.x >> 6;
    int j0 = blockIdx.x * 512 + wv * 128 + lane;
    float acc0[32], acc1[32];
#pragma unroll
    for (int q = 0; q < 32; q++) { acc0[q] = 0.f; acc1[q] = 0.f; }

    for (int kc = 0; kc < K; kc += 64) {
        __syncthreads();
        for (int idx = threadIdx.x; idx < 64 * 32; idx += 256) {
            int n = idx >> 6, k = idx & 63;
            xs[k * 36 + n] = X[(long)(m0 + n) * K + kc + k];
        }
        __syncthreads();
        const float* wp = Wt + (long)kc * Jp + j0;
#pragma unroll 4
        for (int k = 0; k < 64; k++) {
            float w0 = wp[(long)k * Jp];
            float w1 = wp[(long)k * Jp + 64];
            const float4* xv = (const float4*)(xs + k * 36);
#pragma unroll
            for (int q = 0; q < 8; q++) {
                float4 x4 = xv[q];
                acc0[4 * q + 0] += w0 * x4.x;
                acc0[4 * q + 1] += w0 * x4.y;
                acc0[4 * q + 2] += w0 * x4.z;
                acc0[4 * q + 3] += w0 * x4.w;
                acc1[4 * q + 0] += w1 * x4.x;
                acc1[4 * q + 1] += w1 * x4.y;
                acc1[4 * q + 2] += w1 * x4.z;
                acc1[4 * q + 3] += w1 * x4.w;
            }
        }
    }
#pragma unroll
    for (int nn = 0; nn < 32; nn++) {
        long row = remap ? ((long)nn * TT + t) : (long)(m0 + nn);
        float* po = out + row * (remap ? (long)VV : (long)J);
        int ja = j0, jb = j0 + 64;
        if (ja < J) {
            float v = acc0[nn] + bias[ja];
            if (act) v = tanhf(v);
            po[ja] = v;
        }
        if (jb < J) {
            float v = acc1[nn] + bias[jb];
            if (act) v = tanhf(v);
            po[jb] = v;
        }
    }
}

// ---------------------------------------------------------------------------
// Loss: per-(n,t) logsumexp NLL, then mean
// ---------------------------------------------------------------------------
__global__ void loss_rows(const float* __restrict__ out, const int* __restrict__ tokens,
                          float* __restrict__ nll) {
    __shared__ float red[256];
    int row = blockIdx.x;  // n*TT + t
    int n = row / TT, t = row % TT;
    const float* y = out + (long)row * VV;
    int tid = threadIdx.x;
    float m = -1e30f;
    for (int v = tid; v < VV; v += 256) m = fmaxf(m, y[v]);
    red[tid] = m;
    __syncthreads();
    for (int s = 128; s > 0; s >>= 1) {
        if (tid < s) red[tid] = fmaxf(red[tid], red[tid + s]);
        __syncthreads();
    }
    m = red[0];
    __syncthreads();
    float sum = 0.f;
    for (int v = tid; v < VV; v += 256) sum += expf(y[v] - m);
    red[tid] = sum;
    __syncthreads();
    for (int s = 128; s > 0; s >>= 1) {
        if (tid < s) red[tid] += red[tid + s];
        __syncthreads();
    }
    if (tid == 0) {
        int target = (t < TO) ? tokens[n * TO + t] : EOS_ID;
        float lse = m + logf(red[0]);
        nll[row] = lse - y[target];
    }
}

__global__ void loss_final(const float* __restrict__ nll, float* __restrict__ out_loss) {
    __shared__ float red[256];
    int tid = threadIdx.x;
    float s = 0.f;
    for (int i = tid; i < NB * TT; i += 256) s += nll[i];
    red[tid] = s;
    __syncthreads();
    for (int k = 128; k > 0; k >>= 1) {
        if (tid < k) red[tid] += red[tid + k];
        __syncthreads();
    }
    if (tid == 0) *out_loss = red[0] / (float)(NB * TT);
}

// ---------------------------------------------------------------------------
extern "C" void kernel_launch(void* const* d_in, const int* in_sizes, int n_in,
                              void* d_out, int out_size, void* d_ws, size_t ws_size,
                              hipStream_t stream) {
    const int* padded   = (const int*)d_in[0];
    const float* enc    = (const float*)d_in[1];
    const float* emb    = (const float*)d_in[2];
    const float* W_ih0  = (const float*)d_in[3];
    const float* W_hh0  = (const float*)d_in[4];
    const float* b_ih0  = (const float*)d_in[5];
    const float* b_hh0  = (const float*)d_in[6];
    const float* W_ih_r = (const float*)d_in[7];
    const float* W_hh_r = (const float*)d_in[8];
    const float* b_ih_r = (const float*)d_in[9];
    const float* b_hh_r = (const float*)d_in[10];
    const float* W1     = (const float*)d_in[11];
    const float* b1     = (const float*)d_in[12];
    const float* W2     = (const float*)d_in[13];
    const float* b2     = (const float*)d_in[14];
    float* out = (float*)d_out;
    float* ws  = (float*)d_ws;

    // workspace layout (floats), total ~15.37M (61.5 MB)
    float* Wt0  = ws;                     // [1536][2048]
    float* Wt1  = Wt0 + 1536 * 2048;      // [1024][2048]
    float* Wt2  = Wt1 + 1024 * 2048;      // [1024][2048]
    float* Wm1  = Wt2 + 1024 * 2048;      // [1024][512]
    float* R    = Wm1 + 1024 * 512;       // max(part 32*32*2048, Wm2 512*10240)
    float* hbuf = R + 512 * 10240;        // [3][32][512]
    float* cbuf = hbuf + 3 * NB * HH;     // [3][32][512]
    float* attc = cbuf + 3 * NB * HH;     // [32][512]
    float* scor = attc + NB * HH;         // [32][512]
    float* mlpin= scor + NB * TI;         // [65][32][1024]
    float* nll  = mlpin + (long)TT * NB * 1024;  // [2080]
    int*   cnt  = (int*)(nll + 2112);     // barrier counter (aligned pad)
    float* part = R;                      // loop-phase alias
    float* Wm2  = R;                      // final-phase alias (part dead)
    float* y1all= Wt0;                    // final-phase alias (Wt0 dead): [2080][512]

    // init: zero h/c/attc (contiguous) and barrier counter
    hipMemsetAsync(hbuf, 0, (size_t)(7 * NB * HH) * sizeof(float), stream);
    hipMemsetAsync(cnt, 0, 256, stream);
    // weight transposes
    transpose_cat<<<2048, 256, 0, stream>>>(W_ih0, 1024, W_hh0, 512, G4, G4, Wt0);
    transpose_cat<<<2048, 256, 0, stream>>>(W_ih_r, 512, W_hh_r, 512, G4, G4, Wt1);
    transpose_cat<<<2048, 256, 0, stream>>>(W_ih_r + 2048 * 512, 512,
                                            W_hh_r + 2048 * 512, 512, G4, G4, Wt2);
    transpose_cat<<<1024, 256, 0, stream>>>(W1, 1024, nullptr, 0, 512, 512, Wm1);

    // persistent recurrence
    decode_loop<<<NBLK, 256, 0, stream>>>(Wt0, Wt1, Wt2, emb, padded, enc,
                                          b_ih0, b_hh0, b_ih_r, b_hh_r,
                                          hbuf, cbuf, attc, scor, mlpin, part, cnt);

    // deferred MLP over all 2080 rows
    transpose_cat<<<2048, 256, 0, stream>>>(W2, 512, nullptr, 0, VV, 10240, Wm2);
    gemm_full<<<dim3(1, TT), 256, 0, stream>>>(Wm1, 512, 512, 1024, mlpin, b1,
                                               y1all, 1, 0);
    gemm_full<<<dim3(20, TT), 256, 0, stream>>>(Wm2, 10240, VV, 512, y1all, b2,
                                                out, 0, 1);
    loss_rows<<<NB * TT, 256, 0, stream>>>(out, padded, nll);
    loss_final<<<1, 256, 0, stream>>>(nll, out + (long)NB * TT * VV);
}

// Round 4
// 10545.769 us; speedup vs baseline: 1.7725x; 1.7725x over previous
//
#include <hip/hip_runtime.h>
#include <hip/hip_bf16.h>

// Problem constants
#define NB 32      // batch
#define TO 64      // output tokens
#define TT 65      // decode steps (To+1)
#define TI 512     // encoder time
#define VV 10000   // vocab
#define HH 512     // hidden
#define G4 2048    // 4*H
#define SOS_ID 1
#define EOS_ID 2
#define NBLK 256   // persistent grid: 1 block/CU on 256 CUs

// ---------------------------------------------------------------------------
// Coherent (agent-scope, cache-bypassing) accessors for cross-block state.
// Read-only data (weights/enc/emb) stays on the normal cached path.
// ---------------------------------------------------------------------------
__device__ __forceinline__ float2 cload2(const float* p) {
    unsigned long long v = __hip_atomic_load((const unsigned long long*)p,
                                             __ATOMIC_RELAXED, __HIP_MEMORY_SCOPE_AGENT);
    float2 r;
    r.x = __uint_as_float((unsigned)(v & 0xffffffffull));
    r.y = __uint_as_float((unsigned)(v >> 32));
    return r;
}
__device__ __forceinline__ void cstore(float* p, float v) {
    __hip_atomic_store((unsigned*)p, __float_as_uint(v),
                       __ATOMIC_RELAXED, __HIP_MEMORY_SCOPE_AGENT);
}

// Fence-free grid barrier: drain own stores (acked at coherence point),
// block-sync, then counter rendezvous with relaxed atomics. No L2 flush.
__device__ __forceinline__ void gbar(int* cnt, int& bt) {
    asm volatile("s_waitcnt vmcnt(0) lgkmcnt(0)" ::: "memory");
    __syncthreads();
    bt += NBLK;
    if (threadIdx.x == 0) {
        __hip_atomic_fetch_add(cnt, 1, __ATOMIC_RELAXED, __HIP_MEMORY_SCOPE_AGENT);
        while (__hip_atomic_load(cnt, __ATOMIC_RELAXED, __HIP_MEMORY_SCOPE_AGENT) < bt)
            __builtin_amdgcn_s_sleep(2);
    }
    __syncthreads();
}

// ---------------------------------------------------------------------------
// Fused LSTM layer phase. Block owns 8 m x 8 n; wave = gate.
// xs (LDS) holds x[K][8n] as float4 tiles: xs4[kq*8 + nl].
// Thread (g, nl, ml): dot over K of x[n][:] . W_row[g*512+bm*8+ml][:].
// Combine gates in LDS; wave-0 thread applies gating, keeps c in register,
// coherent-stores h.
// ---------------------------------------------------------------------------
template <int IHQ>   // IH row length in float4s: 256 (K_ih=1024) or 128 (512)
__device__ __forceinline__ void lstm_phase(
    const float* __restrict__ Wih, const float* __restrict__ Whh,
    const float* __restrict__ bi, const float* __restrict__ bh,
    float* __restrict__ hout, float& creg, float* __restrict__ mlprow,
    float* smem, int bm, int bn) {
    int tid = threadIdx.x;
    int g = tid >> 6, l = tid & 63, nl = l >> 3, ml = l & 7;
    int j = g * 512 + bm * 8 + ml;
    const float4* xs4 = (const float4*)smem;
    const float4* wa = (const float4*)(Wih + (long)j * (IHQ * 4));
    const float4* wb = (const float4*)(Whh + (long)j * 512);
    float4 acc = {0.f, 0.f, 0.f, 0.f};
#pragma unroll 4
    for (int kq = 0; kq < IHQ; kq++) {
        float4 w4 = wa[kq];
        float4 x4 = xs4[kq * 8 + nl];
        acc.x += w4.x * x4.x; acc.y += w4.y * x4.y;
        acc.z += w4.z * x4.z; acc.w += w4.w * x4.w;
    }
#pragma unroll 4
    for (int kq = 0; kq < 128; kq++) {
        float4 w4 = wb[kq];
        float4 x4 = xs4[(IHQ + kq) * 8 + nl];
        acc.x += w4.x * x4.x; acc.y += w4.y * x4.y;
        acc.z += w4.z * x4.z; acc.w += w4.w * x4.w;
    }
    float s = acc.x + acc.y + acc.z + acc.w + bi[j] + bh[j];
    float* sg = smem + 12288;
    sg[tid] = s;
    __syncthreads();
    if (tid < 64) {
        float gi = sg[tid], gf = sg[tid + 64], gg = sg[tid + 128], go = sg[tid + 192];
        float si = 1.f / (1.f + expf(-gi));
        float sf = 1.f / (1.f + expf(-gf));
        float so = 1.f / (1.f + expf(-go));
        float c2 = sf * creg + si * tanhf(gg);
        creg = c2;
        float hv = so * tanhf(c2);
        int n = bn * 8 + (tid >> 3), m = bm * 8 + (tid & 7);
        cstore(&hout[n * 512 + m], hv);
        if (mlprow) mlprow[(long)n * 1024 + m] = hv;
    }
}

// ---------------------------------------------------------------------------
// Persistent decode loop: 65 steps x 5 phases (L0, L1, L2, scores, SM+apply).
// ---------------------------------------------------------------------------
__global__ __launch_bounds__(256, 1) void decode_loop(
    const float* __restrict__ W_ih0, const float* __restrict__ W_hh0,
    const float* __restrict__ W_ih_r, const float* __restrict__ W_hh_r,
    const float* __restrict__ b_ih0, const float* __restrict__ b_hh0,
    const float* __restrict__ b_ih_r, const float* __restrict__ b_hh_r,
    const float* __restrict__ emb, const int* __restrict__ tokens,
    const float* __restrict__ enc,
    float* __restrict__ hbuf, float* __restrict__ attc,
    float* __restrict__ scor, float* __restrict__ mlpin, int* cnt) {
    __shared__ float smem[12544];   // 48KB x-tile + 1KB combine scratch
    int tid = threadIdx.x, b = blockIdx.x;
    int bt = 0;
    int bm = b & 63, bn = b >> 6;
    float c0r = 0.f, c1r = 0.f, c2r = 0.f;
    float* h0 = hbuf;
    float* h1 = hbuf + NB * HH;
    float* h2 = hbuf + 2 * NB * HH;
    float4* xs4 = (float4*)smem;

    for (int t = 0; t < TT; t++) {
        // ---- phase 1: layer-0 LSTM, x = [emb(tok) | attc | h0], K=1536
        for (int s = tid; s < 3072; s += 256) {
            int kq = s >> 3, n = s & 7, k0 = kq * 4;
            int ng = bn * 8 + n;
            float4 v;
            if (k0 < 512) {
                int row = (t == 0) ? SOS_ID : tokens[ng * TO + t - 1];
                v = *(const float4*)(emb + (long)row * 512 + k0);
            } else if (k0 < 1024) {
                const float* p = attc + ng * 512 + (k0 - 512);
                float2 a = cload2(p), c = cload2(p + 2);
                v.x = a.x; v.y = a.y; v.z = c.x; v.w = c.y;
            } else {
                const float* p = h0 + ng * 512 + (k0 - 1024);
                float2 a = cload2(p), c = cload2(p + 2);
                v.x = a.x; v.y = a.y; v.z = c.x; v.w = c.y;
            }
            xs4[kq * 8 + n] = v;
        }
        __syncthreads();
        lstm_phase<256>(W_ih0, W_hh0, b_ih0, b_hh0, h0, c0r, nullptr, smem, bm, bn);
        gbar(cnt, bt);

        // ---- phase 2: layer-1 LSTM, x = [h0' | h1], K=1024
        for (int s = tid; s < 2048; s += 256) {
            int kq = s >> 3, n = s & 7, k0 = kq * 4;
            int ng = bn * 8 + n;
            const float* p = (k0 < 512) ? (h0 + ng * 512 + k0)
                                        : (h1 + ng * 512 + (k0 - 512));
            float2 a = cload2(p), c = cload2(p + 2);
            float4 v; v.x = a.x; v.y = a.y; v.z = c.x; v.w = c.y;
            xs4[kq * 8 + n] = v;
        }
        __syncthreads();
        lstm_phase<128>(W_ih_r, W_hh_r, b_ih_r, b_hh_r, h1, c1r, nullptr, smem, bm, bn);
        gbar(cnt, bt);

        // ---- phase 3: layer-2 LSTM, x = [h1' | h2], K=1024 (h2' -> mlpin)
        for (int s = tid; s < 2048; s += 256) {
            int kq = s >> 3, n = s & 7, k0 = kq * 4;
            int ng = bn * 8 + n;
            const float* p = (k0 < 512) ? (h1 + ng * 512 + k0)
                                        : (h2 + ng * 512 + (k0 - 512));
            float2 a = cload2(p), c = cload2(p + 2);
            float4 v; v.x = a.x; v.y = a.y; v.z = c.x; v.w = c.y;
            xs4[kq * 8 + n] = v;
        }
        __syncthreads();
        lstm_phase<128>(W_ih_r + 2048 * 512, W_hh_r + 2048 * 512,
                        b_ih_r + G4, b_hh_r + G4, h2, c2r,
                        mlpin + (long)t * NB * 1024, smem, bm, bn);
        gbar(cnt, bt);

        // ---- phase 4: scores[n][ti] = dot(h2'[n], enc[n][ti])
        {
            int n = b & 31, tc = b >> 5;
            float* hs = smem;
            float* sred = smem + 512;
            float2 v = cload2(h2 + n * 512 + tid * 2);
            hs[tid * 2] = v.x; hs[tid * 2 + 1] = v.y;
            __syncthreads();
            int til = tid & 63, ks = tid >> 6;
            int ti = tc * 64 + til;
            const float4* e4 = (const float4*)(enc + ((long)n * TI + ti) * HH + ks * 128);
            const float4* h4 = (const float4*)(hs + ks * 128);
            float4 acc = {0.f, 0.f, 0.f, 0.f};
#pragma unroll 4
            for (int kq = 0; kq < 32; kq++) {
                float4 e = e4[kq], x = h4[kq];
                acc.x += e.x * x.x; acc.y += e.y * x.y;
                acc.z += e.z * x.z; acc.w += e.w * x.w;
            }
            sred[tid] = acc.x + acc.y + acc.z + acc.w;
            __syncthreads();
            if (tid < 64) {
                float s = sred[tid] + sred[tid + 64] + sred[tid + 128] + sred[tid + 192];
                cstore(&scor[n * 512 + tc * 64 + tid], s);
            }
        }
        gbar(cnt, bt);

        // ---- phase 5: softmax + apply -> attc, mlpin[t][:][512:1024]
        {
            int n = b >> 3, hc = b & 7;
            float* sc = smem;
            float* red = smem + 512;
            float* prt = smem + 768;
            float2 v = cload2(scor + n * 512 + tid * 2);
            sc[tid * 2] = v.x; sc[tid * 2 + 1] = v.y;
            __syncthreads();
            float s0 = sc[tid], s1 = sc[tid + 256];
            red[tid] = fmaxf(s0, s1);
            __syncthreads();
            for (int st = 128; st > 0; st >>= 1) {
                if (tid < st) red[tid] = fmaxf(red[tid], red[tid + st]);
                __syncthreads();
            }
            float m = red[0];
            __syncthreads();
            float e0 = expf(s0 - m), e1 = expf(s1 - m);
            red[tid] = e0 + e1;
            __syncthreads();
            for (int st = 128; st > 0; st >>= 1) {
                if (tid < st) red[tid] += red[tid + st];
                __syncthreads();
            }
            float inv = 1.f / red[0];
            __syncthreads();
            sc[tid] = e0 * inv; sc[tid + 256] = e1 * inv;
            __syncthreads();
            int lane = tid & 63, tg = tid >> 6;
            int h = hc * 64 + lane;
            const float* eb = enc + ((long)n * TI + tg * 128) * HH + h;
            float a = 0.f;
#pragma unroll 4
            for (int ti = 0; ti < 128; ti++) a += sc[tg * 128 + ti] * eb[(long)ti * HH];
            prt[tid] = a;
            __syncthreads();
            if (tg == 0) {
                float vv = prt[tid] + prt[tid + 64] + prt[tid + 128] + prt[tid + 192];
                cstore(&attc[n * 512 + h], vv);
                mlpin[((long)t * NB + n) * 1024 + 512 + h] = vv;
            }
        }
        gbar(cnt, bt);
    }
}

// ---------------------------------------------------------------------------
// Weight transpose for tail GEMMs: Wt[k][j] = A[j][k], zero-padded to Jp
// ---------------------------------------------------------------------------
__global__ void transpose_cat(const float* __restrict__ A, int KA,
                              const float* __restrict__ B, int KB,
                              int J, int Jp, float* __restrict__ Wt) {
    int K = KA + KB;
    long total = (long)K * Jp;
    for (long idx = (long)blockIdx.x * 256 + threadIdx.x; idx < total;
         idx += (long)gridDim.x * 256) {
        int j = (int)(idx % Jp);
        int k = (int)(idx / Jp);
        float v = 0.f;
        if (j < J) v = (k < KA) ? A[(long)j * KA + k] : B[(long)j * KB + (k - KA)];
        Wt[idx] = v;
    }
}

// ---------------------------------------------------------------------------
// Full-K batched GEMM with fused bias(+tanh). Thread owns 2 j's (j0, j0+64).
// remap=0: out[row][J]; remap=1: out[(nn*TT+t)*VV + j]
// ---------------------------------------------------------------------------
__global__ void gemm_full(const float* __restrict__ Wt, int Jp, int J, int K,
                          const float* __restrict__ X,
                          const float* __restrict__ bias,
                          float* __restrict__ out, int act, int remap) {
    __shared__ float xs[64 * 36];
    int t = blockIdx.y;
    int m0 = t * 32;
    int lane = threadIdx.x & 63;
    int wv = threadIdx.x >> 6;
    int j0 = blockIdx.x * 512 + wv * 128 + lane;
    float acc0[32], acc1[32];
#pragma unroll
    for (int q = 0; q < 32; q++) { acc0[q] = 0.f; acc1[q] = 0.f; }

    for (int kc = 0; kc < K; kc += 64) {
        __syncthreads();
        for (int idx = threadIdx.x; idx < 64 * 32; idx += 256) {
            int n = idx >> 6, k = idx & 63;
            xs[k * 36 + n] = X[(long)(m0 + n) * K + kc + k];
        }
        __syncthreads();
        const float* wp = Wt + (long)kc * Jp + j0;
#pragma unroll 4
        for (int k = 0; k < 64; k++) {
            float w0 = wp[(long)k * Jp];
            float w1 = wp[(long)k * Jp + 64];
            const float4* xv = (const float4*)(xs + k * 36);
#pragma unroll
            for (int q = 0; q < 8; q++) {
                float4 x4 = xv[q];
                acc0[4 * q + 0] += w0 * x4.x;
                acc0[4 * q + 1] += w0 * x4.y;
                acc0[4 * q + 2] += w0 * x4.z;
                acc0[4 * q + 3] += w0 * x4.w;
                acc1[4 * q + 0] += w1 * x4.x;
                acc1[4 * q + 1] += w1 * x4.y;
                acc1[4 * q + 2] += w1 * x4.z;
                acc1[4 * q + 3] += w1 * x4.w;
            }
        }
    }
#pragma unroll
    for (int nn = 0; nn < 32; nn++) {
        long row = remap ? ((long)nn * TT + t) : (long)(m0 + nn);
        float* po = out + row * (remap ? (long)VV : (long)J);
        int ja = j0, jb = j0 + 64;
        if (ja < J) {
            float v = acc0[nn] + bias[ja];
            if (act) v = tanhf(v);
            po[ja] = v;
        }
        if (jb < J) {
            float v = acc1[nn] + bias[jb];
            if (act) v = tanhf(v);
            po[jb] = v;
        }
    }
}

// ---------------------------------------------------------------------------
// Loss: per-(n,t) logsumexp NLL, then mean
// ---------------------------------------------------------------------------
__global__ void loss_rows(const float* __restrict__ out, const int* __restrict__ tokens,
                          float* __restrict__ nll) {
    __shared__ float red[256];
    int row = blockIdx.x;  // n*TT + t
    int n = row / TT, t = row % TT;
    const float* y = out + (long)row * VV;
    int tid = threadIdx.x;
    float m = -1e30f;
    for (int v = tid; v < VV; v += 256) m = fmaxf(m, y[v]);
    red[tid] = m;
    __syncthreads();
    for (int s = 128; s > 0; s >>= 1) {
        if (tid < s) red[tid] = fmaxf(red[tid], red[tid + s]);
        __syncthreads();
    }
    m = red[0];
    __syncthreads();
    float sum = 0.f;
    for (int v = tid; v < VV; v += 256) sum += expf(y[v] - m);
    red[tid] = sum;
    __syncthreads();
    for (int s = 128; s > 0; s >>= 1) {
        if (tid < s) red[tid] += red[tid + s];
        __syncthreads();
    }
    if (tid == 0) {
        int target = (t < TO) ? tokens[n * TO + t] : EOS_ID;
        float lse = m + logf(red[0]);
        nll[row] = lse - y[target];
    }
}

__global__ void loss_final(const float* __restrict__ nll, float* __restrict__ out_loss) {
    __shared__ float red[256];
    int tid = threadIdx.x;
    float s = 0.f;
    for (int i = tid; i < NB * TT; i += 256) s += nll[i];
    red[tid] = s;
    __syncthreads();
    for (int k = 128; k > 0; k >>= 1) {
        if (tid < k) red[tid] += red[tid + k];
        __syncthreads();
    }
    if (tid == 0) *out_loss = red[0] / (float)(NB * TT);
}

// ---------------------------------------------------------------------------
extern "C" void kernel_launch(void* const* d_in, const int* in_sizes, int n_in,
                              void* d_out, int out_size, void* d_ws, size_t ws_size,
                              hipStream_t stream) {
    const int* padded   = (const int*)d_in[0];
    const float* enc    = (const float*)d_in[1];
    const float* emb    = (const float*)d_in[2];
    const float* W_ih0  = (const float*)d_in[3];
    const float* W_hh0  = (const float*)d_in[4];
    const float* b_ih0  = (const float*)d_in[5];
    const float* b_hh0  = (const float*)d_in[6];
    const float* W_ih_r = (const float*)d_in[7];
    const float* W_hh_r = (const float*)d_in[8];
    const float* b_ih_r = (const float*)d_in[9];
    const float* b_hh_r = (const float*)d_in[10];
    const float* W1     = (const float*)d_in[11];
    const float* b1     = (const float*)d_in[12];
    const float* W2     = (const float*)d_in[13];
    const float* b2     = (const float*)d_in[14];
    float* out = (float*)d_out;
    float* ws  = (float*)d_ws;

    // workspace layout (floats), ~36.4 MB total
    float* Wm1  = ws;                       // [1024][512]
    float* Wm2  = Wm1 + 1024 * 512;         // [512][10240]
    float* hbuf = Wm2 + 512 * 10240;        // [3][32][512]
    float* attc = hbuf + 3 * NB * HH;       // [32][512]
    float* scor = attc + NB * HH;           // [32][512]
    float* mlpin= scor + NB * TI;           // [65][32][1024]
    float* y1all= mlpin + (long)TT * NB * 1024;  // [2080][512]
    float* nll  = y1all + (long)TT * NB * 512;   // [2080]
    int*   cnt  = (int*)(nll + 2112);

    // init: zero h/attc/scor (contiguous) and barrier counter
    hipMemsetAsync(hbuf, 0, (size_t)(5 * NB * HH) * sizeof(float), stream);
    hipMemsetAsync(cnt, 0, 256, stream);

    // persistent recurrence (reads native weight layouts; no transposes needed)
    decode_loop<<<NBLK, 256, 0, stream>>>(W_ih0, W_hh0, W_ih_r, W_hh_r,
                                          b_ih0, b_hh0, b_ih_r, b_hh_r,
                                          emb, padded, enc,
                                          hbuf, attc, scor, mlpin, cnt);

    // deferred MLP over all 2080 rows
    transpose_cat<<<1024, 256, 0, stream>>>(W1, 1024, nullptr, 0, 512, 512, Wm1);
    transpose_cat<<<2048, 256, 0, stream>>>(W2, 512, nullptr, 0, VV, 10240, Wm2);
    gemm_full<<<dim3(1, TT), 256, 0, stream>>>(Wm1, 512, 512, 1024, mlpin, b1,
                                               y1all, 1, 0);
    gemm_full<<<dim3(20, TT), 256, 0, stream>>>(Wm2, 10240, VV, 512, y1all, b2,
                                                out, 0, 1);
    loss_rows<<<NB * TT, 256, 0, stream>>>(out, padded, nll);
    loss_final<<<1, 256, 0, stream>>>(nll, out + (long)NB * TT * VV);
}